// Round 10
// baseline (234.628 us; speedup 1.0000x reference)
//
#include <hip/hip_runtime.h>
#include <stdint.h>

#define N_ANCH 12288
#define NCLS 64
#define TOTW 192              // 64-box words in patch-sorted (s) space
#define CAPO 1024             // overflow (word,mask) slots per row

typedef unsigned long long u64;
typedef unsigned int u32;
typedef unsigned short u16;
typedef unsigned char u8;

struct __align__(16) PRec { float4 b; float area; u32 big; u64 k64; };  // 32B

// IoU > 0.5 predicate, replicating numpy op order/rounding exactly (no FMA contraction).
__device__ __forceinline__ bool iou_gt(float4 a, float fa, float4 b, float fb) {
    float xx1 = fmaxf(a.x, b.x);
    float yy1 = fmaxf(a.y, b.y);
    float xx2 = fminf(a.z, b.z);
    float yy2 = fminf(a.w, b.w);
    float dx = fmaxf(__fsub_rn(xx2, xx1), 0.0f);
    float dy = fmaxf(__fsub_rn(yy2, yy1), 0.0f);
    float inter = __fmul_rn(dx, dy);
    float denom = __fadd_rn(__fsub_rn(__fadd_rn(fa, fb), inter), 1e-9f);
    float iou = __fdiv_rn(inter, denom);
    return iou > 0.5f;
}

// s-index (patch-major) from original index
__device__ __forceinline__ int s_of(int i) {
    int y = i >> 7, x = i & 127;
    int w = ((y >> 3) << 4) | (x >> 3);       // patch id: py*16+px
    int l = ((y & 7) << 3) | (x & 7);         // lane in 8x8 patch
    return (w << 6) | l;
}
__device__ __forceinline__ int orig_of(int s) {
    int w = s >> 6, l = s & 63;
    int py = w >> 4, px = w & 15, ly = l >> 3, lx = l & 7;
    return (((py << 3) + ly) << 7) + ((px << 3) + lx);
}

// ---------------- decode: orig-order boxes/score + patch-order PRec; zero rec headers ----------------
__global__ void decode_kernel(const float4* __restrict__ loc, const float* __restrict__ cls,
                              float4* __restrict__ boxes, float* __restrict__ score,
                              PRec* __restrict__ pall, u64* __restrict__ rec8) {
    int i = blockIdx.x * 256 + threadIdx.x;
    if (i >= N_ANCH) return;
    float4 l = loc[i];
    int y = i >> 7;        // FM_W = 128
    int x = i & 127;
    float cx = (x + 0.5f) * 8.0f;   // exact
    float cy = (y + 0.5f) * 8.0f;   // exact
    float px = __fadd_rn(__fmul_rn(l.x, 32.0f), cx);
    float py = __fadd_rn(__fmul_rn(l.y, 32.0f), cy);
    float pw = __fmul_rn(expf(l.z), 32.0f);
    float ph = __fmul_rn(expf(l.w), 32.0f);
    float hx = __fmul_rn(pw, 0.5f);
    float hy = __fmul_rn(ph, 0.5f);
    float x1 = __fsub_rn(px, hx), y1 = __fsub_rn(py, hy);
    float x2 = __fadd_rn(px, hx), y2 = __fadd_rn(py, hy);
    float4 b; b.x = x1; b.y = y1; b.z = x2; b.w = y2;
    boxes[i] = b;
    float ar = __fmul_rn(__fsub_rn(x2, x1), __fsub_rn(y2, y1));

    const float4* cr = (const float4*)(cls + (size_t)i * NCLS);
    float mx = -INFINITY;
#pragma unroll
    for (int k = 0; k < 16; ++k) {
        float4 v = cr[k];
        mx = fmaxf(mx, fmaxf(fmaxf(v.x, v.y), fmaxf(v.z, v.w)));
    }
    float s;
    if (mx >= 0.0f) {
        float e = expf(-mx);
        s = __fdiv_rn(1.0f, __fadd_rn(1.0f, e));
    } else {
        float e = expf(mx);
        s = __fdiv_rn(e, __fadd_rn(1.0f, e));
    }
    score[i] = s;
    float se = (s > 0.5f) ? s : -INFINITY;   // score_eff
    u32 u = __float_as_uint(se);
    u = (u & 0x80000000u) ? ~u : (u | 0x80000000u);   // ascending-ordered uint; valid >= 0x80000000

    int si = s_of(i);
    PRec r;
    r.b = b;
    r.area = ar;
    r.big = ((x2 - x1) > 128.0f) || ((y2 - y1) > 128.0f);
    r.k64 = ((u64)u << 32) | (u32)(~(u32)i);          // earlier(j,i) <=> k64_j > k64_i
    pall[si] = r;
    rec8[(size_t)si * 8] = 0ull;
}

// ---------------- pairs: wave-per-row, wave-uniform word-bbox skip + outlier pass ----------------
// 256 blocks x 1024 thr (16 waves). Phase A: block builds 192 trimmed word bboxes + LDS outlier list.
// Phase B: each wave handles 3 rows; per row loops 192 words (uniform skip) + outlier chunks.
__global__ void __launch_bounds__(1024)
pairs_kernel(const PRec* __restrict__ pall, u64* __restrict__ rec8,
             u8* __restrict__ ovw, u64* __restrict__ ovm) {
    __shared__ float4 wb[TOTW];
    __shared__ u16 olist[N_ANCH];
    __shared__ u32 oc;
    int tid = threadIdx.x;
    int wave = tid >> 6, lane = tid & 63;
    if (tid == 0) oc = 0;
    __syncthreads();

    // Phase A
    for (int ww = 0; ww < 12; ++ww) {
        int W = wave * 12 + ww;
        int idx = (W << 6) + lane;
        PRec rc = pall[idx];
        bool big = rc.big != 0;
        float ax1 = big ? INFINITY : rc.b.x;
        float ay1 = big ? INFINITY : rc.b.y;
        float ax2 = big ? -INFINITY : rc.b.z;
        float ay2 = big ? -INFINITY : rc.b.w;
#pragma unroll
        for (int off = 1; off < 64; off <<= 1) {
            ax1 = fminf(ax1, __shfl_xor(ax1, off));
            ay1 = fminf(ay1, __shfl_xor(ay1, off));
            ax2 = fmaxf(ax2, __shfl_xor(ax2, off));
            ay2 = fmaxf(ay2, __shfl_xor(ay2, off));
        }
        if (lane == 0) { float4 v; v.x = ax1; v.y = ay1; v.z = ax2; v.w = ay2; wb[W] = v; }
        u64 bm = __ballot(big);
        u32 base = 0;
        if (lane == 0 && bm) base = atomicAdd(&oc, (u32)__popcll(bm));
        base = __shfl(base, 0);
        if (big) {
            u32 rkk = (u32)__popcll(bm & ((lane == 0) ? 0ull : (~0ull >> (64 - lane))));
            olist[base + rkk] = (u16)idx;
        }
    }
    __syncthreads();
    u32 ocn = oc;

    // Phase B
    for (int rr = 0; rr < 3; ++rr) {
        int r = (blockIdx.x * 16 + wave) * 3 + rr;
        PRec ri = pall[r];
        float4 bi = ri.b;
        float ai = ri.area;
        u64 ki = ri.k64;
        u32 wcslot;
        for (int W = 0; W < TOTW; ++W) {
            float4 h = wb[W];
            bool pass = (bi.x < h.z) && (h.x < bi.z) && (bi.y < h.w) && (h.y < bi.w);
            if (pass) {
                int j = (W << 6) + lane;
                PRec rj = pall[j];
                bool pred = (rj.k64 > ki) && iou_gt(bi, ai, rj.b, rj.area);
                u64 m = __ballot(pred);
                if (lane == 0 && m) {
                    wcslot = atomicAdd((u32*)&rec8[(size_t)r * 8], 1u);
                    if (wcslot < 6) {
                        ((u8*)&rec8[(size_t)r * 8 + 1])[wcslot] = (u8)W;
                        rec8[(size_t)r * 8 + 2 + wcslot] = m;
                    } else {
                        u32 o = wcslot - 6;
                        ovw[(size_t)r * CAPO + o] = (u8)W;
                        ovm[(size_t)r * CAPO + o] = m;
                    }
                }
            }
        }
        for (u32 k = 0; k < ocn; k += 64) {
            u32 t = k + lane;
            bool live = t < ocn;
            int o = live ? (int)olist[t] : 0;
            PRec ro = pall[o];
            bool pred = live && (ro.k64 > ki) && iou_gt(bi, ai, ro.b, ro.area);
            if (pred) {
                u32 slot = atomicAdd((u32*)&rec8[(size_t)r * 8], 1u);
                u8 Wo = (u8)(o >> 6);
                u64 m = 1ull << (o & 63);
                if (slot < 6) {
                    ((u8*)&rec8[(size_t)r * 8 + 1])[slot] = Wo;
                    rec8[(size_t)r * 8 + 2 + slot] = m;
                } else {
                    u32 oo = slot - 6;
                    ovw[(size_t)r * CAPO + oo] = Wo;
                    ovm[(size_t)r * CAPO + oo] = m;
                }
            }
        }
    }
}

// ---------------- solve: synchronous fixpoint; s-space; fused output ----------------
__global__ void __launch_bounds__(1024)
solve_kernel(const u64* __restrict__ rec8, const u8* __restrict__ ovw,
             const u64* __restrict__ ovm, const float4* __restrict__ boxes,
             const float* __restrict__ score, float* __restrict__ out) {
    __shared__ u64 kept[TOTW];
    __shared__ u64 dec[TOTW];
    __shared__ int changed;
    int tid = threadIdx.x;
    for (int k = tid; k < TOTW; k += 1024) { kept[k] = 0ull; dec[k] = 0ull; }
    __syncthreads();

    u32 undec = 0;
#pragma unroll
    for (int b = 0; b < 12; ++b) {
        int i = tid + (b << 10);                  // s-space
        if (score[orig_of(i)] > 0.5f) undec |= (1u << b);
        else atomicOr(&dec[i >> 6], 1ull << (i & 63));
    }
    __syncthreads();

    for (int round = 0; round < 12300; ++round) {
        if (tid == 0) changed = 0;
        __syncthreads();
        u32 dkeep = 0, dkill = 0;
        u32 u = undec;
        while (u) {
            int b = __ffs(u) - 1; u &= u - 1;
            int i = tid + (b << 10);
            const ulonglong4* rp = (const ulonglong4*)&rec8[(size_t)i * 8];
            ulonglong4 RA = rp[0];
            u32 wc = (u32)RA.x;
            u64 wb = RA.y;
            u32 w0 = (u32)(wb & 0xFF), w1 = (u32)((wb >> 8) & 0xFF);
            u64 anyk = 0, anyu = 0;
            if (wc > 0) { u64 m = RA.z; anyu |= m & ~dec[w0]; anyk |= m & kept[w0]; }
            if (wc > 1) { u64 m = RA.w; anyu |= m & ~dec[w1]; anyk |= m & kept[w1]; }
            if (wc > 2) {
                ulonglong4 RB = rp[1];
                u32 w2 = (u32)((wb >> 16) & 0xFF), w3 = (u32)((wb >> 24) & 0xFF);
                u32 w4 = (u32)((wb >> 32) & 0xFF), w5 = (u32)((wb >> 40) & 0xFF);
                { u64 m = RB.x; anyu |= m & ~dec[w2]; anyk |= m & kept[w2]; }
                if (wc > 3) { u64 m = RB.y; anyu |= m & ~dec[w3]; anyk |= m & kept[w3]; }
                if (wc > 4) { u64 m = RB.z; anyu |= m & ~dec[w4]; anyk |= m & kept[w4]; }
                if (wc > 5) { u64 m = RB.w; anyu |= m & ~dec[w5]; anyk |= m & kept[w5]; }
            }
            if (wc > 6) {
                u32 we = (wc <= (u32)(6 + CAPO)) ? wc : (u32)(6 + CAPO);
                for (u32 k = 6; k < we; ++k) {
                    u32 Wo = ovw[(size_t)i * CAPO + (k - 6)];
                    u64 m = ovm[(size_t)i * CAPO + (k - 6)];
                    anyu |= m & ~dec[Wo]; anyk |= m & kept[Wo];
                }
            }
            if (anyk) dkill |= (1u << b);
            else if (!anyu) dkeep |= (1u << b);
        }
        __syncthreads();
        u32 dmask = dkeep | dkill;
        if (dmask) {
            changed = 1;
            u32 m2 = dmask;
            while (m2) {
                int b = __ffs(m2) - 1; m2 &= m2 - 1;
                int i = tid + (b << 10);
                if (dkeep & (1u << b)) atomicOr(&kept[i >> 6], 1ull << (i & 63));
                atomicOr(&dec[i >> 6], 1ull << (i & 63));
            }
            undec &= ~dmask;
        }
        __syncthreads();
        int ch = changed;
        __syncthreads();
        if (ch == 0) break;
    }

    // output: map s -> orig
#pragma unroll
    for (int b = 0; b < 12; ++b) {
        int i = tid + (b << 10);
        int og = orig_of(i);
        float m = ((kept[i >> 6] >> (i & 63)) & 1ull) ? 1.0f : 0.0f;
        float4 bx = boxes[og];
        float s = score[og];
        out[(size_t)og * 5 + 0] = __fmul_rn(bx.x, m);
        out[(size_t)og * 5 + 1] = __fmul_rn(bx.y, m);
        out[(size_t)og * 5 + 2] = __fmul_rn(bx.z, m);
        out[(size_t)og * 5 + 3] = __fmul_rn(bx.w, m);
        out[(size_t)og * 5 + 4] = __fmul_rn(s, m);
    }
}

extern "C" void kernel_launch(void* const* d_in, const int* in_sizes, int n_in,
                              void* d_out, int out_size, void* d_ws, size_t ws_size,
                              hipStream_t stream) {
    const float4* loc = (const float4*)d_in[0];
    const float* cls = (const float*)d_in[1];
    char* ws = (char*)d_ws;

    float4* boxes = (float4*)(ws + 0);            // 196608
    float*  score = (float*) (ws + 196608);       // 49152
    PRec*   pall  = (PRec*)  (ws + 245760);       // 12288*32 = 393216
    u64*    rec8  = (u64*)   (ws + 638976);       // 12288*64 = 786432
    u8*     ovw   = (u8*)    (ws + 1425408);      // 12288*1024 = 12582912
    u64*    ovm   = (u64*)   (ws + 14008320);     // 12288*1024*8 = 100663296 (end ~114.7MB)
    float*  out   = (float*)d_out;

    decode_kernel<<<48, 256, 0, stream>>>(loc, cls, boxes, score, pall, rec8);
    pairs_kernel<<<256, 1024, 0, stream>>>(pall, rec8, ovw, ovm);
    solve_kernel<<<1, 1024, 0, stream>>>(rec8, ovw, ovm, boxes, score, out);
}

// Round 11
// 196.692 us; speedup vs baseline: 1.1929x; 1.1929x over previous
//
#include <hip/hip_runtime.h>
#include <stdint.h>

#define N_ANCH 12288
#define NCLS 64
#define TOTW 192              // 64-box words in patch-sorted (s) space
#define CAPO 1024             // overflow (word,mask) slots per row

typedef unsigned long long u64;
typedef unsigned int u32;
typedef unsigned short u16;
typedef unsigned char u8;

struct __align__(16) PRec { float4 b; float area; u32 big; u64 k64; };  // 32B

// IoU > 0.5 predicate, replicating numpy op order/rounding exactly (no FMA contraction).
__device__ __forceinline__ bool iou_gt(float4 a, float fa, float4 b, float fb) {
    float xx1 = fmaxf(a.x, b.x);
    float yy1 = fmaxf(a.y, b.y);
    float xx2 = fminf(a.z, b.z);
    float yy2 = fminf(a.w, b.w);
    float dx = fmaxf(__fsub_rn(xx2, xx1), 0.0f);
    float dy = fmaxf(__fsub_rn(yy2, yy1), 0.0f);
    float inter = __fmul_rn(dx, dy);
    float denom = __fadd_rn(__fsub_rn(__fadd_rn(fa, fb), inter), 1e-9f);
    float iou = __fdiv_rn(inter, denom);
    return iou > 0.5f;
}

// order-preserving float<->uint maps (ascending)
__device__ __forceinline__ u32 encf(float f) {
    u32 t = __float_as_uint(f);
    return (t & 0x80000000u) ? ~t : (t | 0x80000000u);
}
__device__ __forceinline__ float decf(u32 u) {
    u32 bits = (u & 0x80000000u) ? (u ^ 0x80000000u) : ~u;
    return __uint_as_float(bits);
}

// s-index (patch-major) mapping
__device__ __forceinline__ int s_of(int i) {
    int y = i >> 7, x = i & 127;
    int w = ((y >> 3) << 4) | (x >> 3);
    int l = ((y & 7) << 3) | (x & 7);
    return (w << 6) | l;
}
__device__ __forceinline__ int orig_of(int s) {
    int w = s >> 6, l = s & 63;
    int py = w >> 4, px = w & 15, ly = l >> 3, lx = l & 7;
    return (((py << 3) + ly) << 7) + ((px << 3) + lx);
}

// ---------------- decode: PRec + trimmed word hulls (atomics) + outlier list ----------------
__global__ void decode_kernel(const float4* __restrict__ loc, const float* __restrict__ cls,
                              float4* __restrict__ boxes, float* __restrict__ score,
                              PRec* __restrict__ pall, u64* __restrict__ rec8,
                              u32* __restrict__ hx1n, u32* __restrict__ hy1n,
                              u32* __restrict__ hx2e, u32* __restrict__ hy2e,
                              u32* __restrict__ ocp, u16* __restrict__ olist) {
    int i = blockIdx.x * 256 + threadIdx.x;
    if (i >= N_ANCH) return;
    float4 l = loc[i];
    int y = i >> 7;        // FM_W = 128
    int x = i & 127;
    float cx = (x + 0.5f) * 8.0f;   // exact
    float cy = (y + 0.5f) * 8.0f;   // exact
    float px = __fadd_rn(__fmul_rn(l.x, 32.0f), cx);
    float py = __fadd_rn(__fmul_rn(l.y, 32.0f), cy);
    float pw = __fmul_rn(expf(l.z), 32.0f);
    float ph = __fmul_rn(expf(l.w), 32.0f);
    float hx = __fmul_rn(pw, 0.5f);
    float hy = __fmul_rn(ph, 0.5f);
    float x1 = __fsub_rn(px, hx), y1 = __fsub_rn(py, hy);
    float x2 = __fadd_rn(px, hx), y2 = __fadd_rn(py, hy);
    float4 b; b.x = x1; b.y = y1; b.z = x2; b.w = y2;
    boxes[i] = b;
    float ar = __fmul_rn(__fsub_rn(x2, x1), __fsub_rn(y2, y1));

    const float4* cr = (const float4*)(cls + (size_t)i * NCLS);
    float mx = -INFINITY;
#pragma unroll
    for (int k = 0; k < 16; ++k) {
        float4 v = cr[k];
        mx = fmaxf(mx, fmaxf(fmaxf(v.x, v.y), fmaxf(v.z, v.w)));
    }
    float s;
    if (mx >= 0.0f) {
        float e = expf(-mx);
        s = __fdiv_rn(1.0f, __fadd_rn(1.0f, e));
    } else {
        float e = expf(mx);
        s = __fdiv_rn(e, __fadd_rn(1.0f, e));
    }
    score[i] = s;
    float se = (s > 0.5f) ? s : -INFINITY;   // score_eff
    u32 u = __float_as_uint(se);
    u = (u & 0x80000000u) ? ~u : (u | 0x80000000u);   // ascending; valid >= 0x80000000

    int si = s_of(i);
    int W = si >> 6;
    bool valid = (u >= 0x80000000u);
    bool big = ((x2 - x1) > 128.0f) || ((y2 - y1) > 128.0f);
    PRec r;
    r.b = b;
    r.area = ar;
    r.big = big;
    r.k64 = ((u64)u << 32) | (u32)(~(u32)i);          // earlier(j,i) <=> k64_j > k64_i
    pall[si] = r;
    rec8[(size_t)si * 8] = 0ull;

    if (valid) {
        if (!big) {
            atomicMax(&hx1n[W], ~encf(x1));
            atomicMax(&hy1n[W], ~encf(y1));
            atomicMax(&hx2e[W], encf(x2));
            atomicMax(&hy2e[W], encf(y2));
        } else {
            u32 o = atomicAdd(ocp, 1u);
            olist[o] = (u16)si;
        }
    }
}

// ---------------- pairs: phase1 window masks (VALU) -> phase2 dense per-word exec (LDS) ----------------
// 192 blocks x 1024 thr. Block rg owns rows = word rg's 64 boxes.
__global__ void __launch_bounds__(1024)
pairs_kernel(const PRec* __restrict__ pall, u64* __restrict__ rec8,
             u8* __restrict__ ovw, u64* __restrict__ ovm,
             const u32* __restrict__ hx1n, const u32* __restrict__ hy1n,
             const u32* __restrict__ hx2e, const u32* __restrict__ hy2e,
             const u32* __restrict__ ocp, const u16* __restrict__ olist) {
    __shared__ float4 rbox[64];  __shared__ float rarea[64];  __shared__ u64 rk[64];
    __shared__ float4 wb[TOTW];
    __shared__ u64 rowmask[TOTW];
    __shared__ u8 rowlist[64];
    __shared__ float4 jbox[64];  __shared__ float jarea[64];  __shared__ u64 jk[64];
    __shared__ float4 obox[512]; __shared__ float oarea[512]; __shared__ u64 okey[512];
    __shared__ u16 osid[512];

    int tid = threadIdx.x;
    int wave = tid >> 6, lane = tid & 63;
    int rg = blockIdx.x;

    if (tid < 64) {
        PRec p = pall[(rg << 6) + tid];
        rbox[tid] = p.b; rarea[tid] = p.area; rk[tid] = p.k64;
    }
    if (tid < TOTW) {
        float4 h;
        h.x = decf(~hx1n[tid]); h.y = decf(~hy1n[tid]);
        h.z = decf(hx2e[tid]);  h.w = decf(hy2e[tid]);
        wb[tid] = h;                       // empty word -> NaNs -> never passes
        rowmask[tid] = 0ull;
    }
    __syncthreads();

    // phase 1: 64 rows x 192 words window tests
    {
        int row = tid >> 4, wq = tid & 15;
        float4 bi = rbox[row];
        bool v = (rk[row] >> 63) != 0ull;
#pragma unroll
        for (int k = 0; k < 12; ++k) {
            int W = wq * 12 + k;
            float4 h = wb[W];
            bool pass = v && (bi.x < h.z) && (h.x < bi.z) && (bi.y < h.w) && (h.y < bi.w);
            if (pass) atomicOr(&rowmask[W], 1ull << row);
        }
    }
    __syncthreads();

    // phase 2: per active word, stage 64 j's then dense wave-per-row exec
    for (int W = 0; W < TOTW; ++W) {
        u64 m = rowmask[W];
        if (m == 0ull) continue;
        __syncthreads();                   // protect jbox from previous iteration
        if (tid < 64) {
            PRec p = pall[(W << 6) + tid];
            jbox[tid] = p.b; jarea[tid] = p.area; jk[tid] = p.k64;
            if ((m >> tid) & 1ull)
                rowlist[__popcll(m & ((1ull << tid) - 1ull))] = (u8)tid;
        }
        __syncthreads();
        int n = __popcll(m);
        for (int t = wave; t < n; t += 16) {
            int row = rowlist[t];
            float4 bi = rbox[row];
            float ai = rarea[row];
            u64 ki = rk[row];
            bool pred = (jk[lane] > ki) && iou_gt(bi, ai, jbox[lane], jarea[lane]);
            u64 mm = __ballot(pred);
            if (lane == 0 && mm) {
                int r = (rg << 6) + row;
                u32 slot = atomicAdd((u32*)&rec8[(size_t)r * 8], 1u);
                if (slot < 6) {
                    ((u8*)&rec8[(size_t)r * 8 + 1])[slot] = (u8)W;
                    rec8[(size_t)r * 8 + 2 + slot] = mm;
                } else if (slot < 6u + CAPO) {
                    ovw[(size_t)r * CAPO + slot - 6] = (u8)W;
                    ovm[(size_t)r * CAPO + slot - 6] = mm;
                }
            }
        }
    }

    // phase 3: all rows vs outlier (big) boxes, staged in chunks of 512
    u32 ocn = *ocp;
    for (u32 base = 0; base < ocn; base += 512) {
        u32 cnt = (ocn - base < 512u) ? (ocn - base) : 512u;
        __syncthreads();
        if (tid < cnt) {
            u16 sj = olist[base + tid];
            PRec p = pall[sj];
            obox[tid] = p.b; oarea[tid] = p.area; okey[tid] = p.k64; osid[tid] = sj;
        }
        __syncthreads();
        for (int rr = 0; rr < 4; ++rr) {
            int row = wave * 4 + rr;
            u64 ki = rk[row];
            if (!(ki >> 63)) continue;     // invalid row: wave-uniform skip
            float4 bi = rbox[row];
            float ai = rarea[row];
            for (u32 j0 = 0; j0 < cnt; j0 += 64) {
                u32 jj = j0 + lane;
                bool pred = false;
                u16 sj = 0;
                if (jj < cnt) {
                    sj = osid[jj];
                    pred = (okey[jj] > ki) && iou_gt(bi, ai, obox[jj], oarea[jj]);
                }
                if (pred) {
                    int r = (rg << 6) + row;
                    u32 slot = atomicAdd((u32*)&rec8[(size_t)r * 8], 1u);
                    u8 Wo = (u8)(sj >> 6);
                    u64 mm = 1ull << (sj & 63);
                    if (slot < 6) {
                        ((u8*)&rec8[(size_t)r * 8 + 1])[slot] = Wo;
                        rec8[(size_t)r * 8 + 2 + slot] = mm;
                    } else if (slot < 6u + CAPO) {
                        ovw[(size_t)r * CAPO + slot - 6] = Wo;
                        ovm[(size_t)r * CAPO + slot - 6] = mm;
                    }
                }
            }
        }
    }
}

// ---------------- solve: synchronous fixpoint; s-space; fused output ----------------
__global__ void __launch_bounds__(1024)
solve_kernel(const u64* __restrict__ rec8, const u8* __restrict__ ovw,
             const u64* __restrict__ ovm, const float4* __restrict__ boxes,
             const float* __restrict__ score, float* __restrict__ out) {
    __shared__ u64 kept[TOTW];
    __shared__ u64 dec[TOTW];
    __shared__ int changed;
    int tid = threadIdx.x;
    for (int k = tid; k < TOTW; k += 1024) { kept[k] = 0ull; dec[k] = 0ull; }
    __syncthreads();

    u32 undec = 0;
#pragma unroll
    for (int b = 0; b < 12; ++b) {
        int i = tid + (b << 10);                  // s-space
        if (score[orig_of(i)] > 0.5f) undec |= (1u << b);
        else atomicOr(&dec[i >> 6], 1ull << (i & 63));
    }
    __syncthreads();

    for (int round = 0; round < 12300; ++round) {
        if (tid == 0) changed = 0;
        __syncthreads();
        u32 dkeep = 0, dkill = 0;
        u32 u = undec;
        while (u) {
            int b = __ffs(u) - 1; u &= u - 1;
            int i = tid + (b << 10);
            const ulonglong4* rp = (const ulonglong4*)&rec8[(size_t)i * 8];
            ulonglong4 RA = rp[0];
            u32 wc = (u32)RA.x;
            u64 wb = RA.y;
            u32 w0 = (u32)(wb & 0xFF), w1 = (u32)((wb >> 8) & 0xFF);
            u64 anyk = 0, anyu = 0;
            if (wc > 0) { u64 m = RA.z; anyu |= m & ~dec[w0]; anyk |= m & kept[w0]; }
            if (wc > 1) { u64 m = RA.w; anyu |= m & ~dec[w1]; anyk |= m & kept[w1]; }
            if (wc > 2) {
                ulonglong4 RB = rp[1];
                u32 w2 = (u32)((wb >> 16) & 0xFF), w3 = (u32)((wb >> 24) & 0xFF);
                u32 w4 = (u32)((wb >> 32) & 0xFF), w5 = (u32)((wb >> 40) & 0xFF);
                { u64 m = RB.x; anyu |= m & ~dec[w2]; anyk |= m & kept[w2]; }
                if (wc > 3) { u64 m = RB.y; anyu |= m & ~dec[w3]; anyk |= m & kept[w3]; }
                if (wc > 4) { u64 m = RB.z; anyu |= m & ~dec[w4]; anyk |= m & kept[w4]; }
                if (wc > 5) { u64 m = RB.w; anyu |= m & ~dec[w5]; anyk |= m & kept[w5]; }
            }
            if (wc > 6) {
                u32 we = (wc <= (u32)(6 + CAPO)) ? wc : (u32)(6 + CAPO);
                for (u32 k = 6; k < we; ++k) {
                    u32 Wo = ovw[(size_t)i * CAPO + (k - 6)];
                    u64 m = ovm[(size_t)i * CAPO + (k - 6)];
                    anyu |= m & ~dec[Wo]; anyk |= m & kept[Wo];
                }
            }
            if (anyk) dkill |= (1u << b);
            else if (!anyu) dkeep |= (1u << b);
        }
        __syncthreads();
        u32 dmask = dkeep | dkill;
        if (dmask) {
            changed = 1;
            u32 m2 = dmask;
            while (m2) {
                int b = __ffs(m2) - 1; m2 &= m2 - 1;
                int i = tid + (b << 10);
                if (dkeep & (1u << b)) atomicOr(&kept[i >> 6], 1ull << (i & 63));
                atomicOr(&dec[i >> 6], 1ull << (i & 63));
            }
            undec &= ~dmask;
        }
        __syncthreads();
        int ch = changed;
        __syncthreads();
        if (ch == 0) break;
    }

    // output: map s -> orig
#pragma unroll
    for (int b = 0; b < 12; ++b) {
        int i = tid + (b << 10);
        int og = orig_of(i);
        float m = ((kept[i >> 6] >> (i & 63)) & 1ull) ? 1.0f : 0.0f;
        float4 bx = boxes[og];
        float s = score[og];
        out[(size_t)og * 5 + 0] = __fmul_rn(bx.x, m);
        out[(size_t)og * 5 + 1] = __fmul_rn(bx.y, m);
        out[(size_t)og * 5 + 2] = __fmul_rn(bx.z, m);
        out[(size_t)og * 5 + 3] = __fmul_rn(bx.w, m);
        out[(size_t)og * 5 + 4] = __fmul_rn(s, m);
    }
}

extern "C" void kernel_launch(void* const* d_in, const int* in_sizes, int n_in,
                              void* d_out, int out_size, void* d_ws, size_t ws_size,
                              hipStream_t stream) {
    const float4* loc = (const float4*)d_in[0];
    const float* cls = (const float*)d_in[1];
    char* ws = (char*)d_ws;

    float4* boxes = (float4*)(ws + 0);            // 196608
    float*  score = (float*) (ws + 196608);       // 49152
    PRec*   pall  = (PRec*)  (ws + 245760);       // 393216
    u64*    rec8  = (u64*)   (ws + 638976);       // 786432
    u32*    hx1n  = (u32*)   (ws + 1425408);      // 768
    u32*    hy1n  = (u32*)   (ws + 1426176);      // 768
    u32*    hx2e  = (u32*)   (ws + 1426944);      // 768
    u32*    hy2e  = (u32*)   (ws + 1427712);      // 768
    u32*    ocp   = (u32*)   (ws + 1428480);      // 4 (+pad)
    u16*    olist = (u16*)   (ws + 1428544);      // 24576
    u8*     ovw   = (u8*)    (ws + 1453120);      // 12582912
    u64*    ovm   = (u64*)   (ws + 14036032);     // 100663296 (end ~114.7MB)
    float*  out   = (float*)d_out;

    hipMemsetAsync(ws + 1425408, 0, 3140, stream);   // hulls + oc
    decode_kernel<<<48, 256, 0, stream>>>(loc, cls, boxes, score, pall, rec8,
                                          hx1n, hy1n, hx2e, hy2e, ocp, olist);
    pairs_kernel<<<TOTW, 1024, 0, stream>>>(pall, rec8, ovw, ovm,
                                            hx1n, hy1n, hx2e, hy2e, ocp, olist);
    solve_kernel<<<1, 1024, 0, stream>>>(rec8, ovw, ovm, boxes, score, out);
}

// Round 12
// 158.319 us; speedup vs baseline: 1.4820x; 1.2424x over previous
//
#include <hip/hip_runtime.h>
#include <stdint.h>

#define N_ANCH 12288
#define NCLS 64
#define TOTW 192              // 64-box words in patch-sorted (s) space
#define CAPO 1024             // overflow (word,mask) slots per row
#define OCAP 4096             // outlier list capacity (mean ~1950, +50 sigma)

typedef unsigned long long u64;
typedef unsigned int u32;
typedef unsigned short u16;
typedef unsigned char u8;

// IoU > 0.5 predicate, replicating numpy op order/rounding exactly (no FMA contraction).
__device__ __forceinline__ bool iou_gt(float4 a, float fa, float4 b, float fb) {
    float xx1 = fmaxf(a.x, b.x);
    float yy1 = fmaxf(a.y, b.y);
    float xx2 = fminf(a.z, b.z);
    float yy2 = fminf(a.w, b.w);
    float dx = fmaxf(__fsub_rn(xx2, xx1), 0.0f);
    float dy = fmaxf(__fsub_rn(yy2, yy1), 0.0f);
    float inter = __fmul_rn(dx, dy);
    float denom = __fadd_rn(__fsub_rn(__fadd_rn(fa, fb), inter), 1e-9f);
    float iou = __fdiv_rn(inter, denom);
    return iou > 0.5f;
}
__device__ __forceinline__ float area_of(float4 b) {
    return __fmul_rn(__fsub_rn(b.z, b.x), __fsub_rn(b.w, b.y));
}

// order-preserving float<->uint maps (ascending)
__device__ __forceinline__ u32 encf(float f) {
    u32 t = __float_as_uint(f);
    return (t & 0x80000000u) ? ~t : (t | 0x80000000u);
}
__device__ __forceinline__ float decf(u32 u) {
    u32 bits = (u & 0x80000000u) ? (u ^ 0x80000000u) : ~u;
    return __uint_as_float(bits);
}

// s-index (patch-major) mapping
__device__ __forceinline__ int s_of(int i) {
    int y = i >> 7, x = i & 127;
    int w = ((y >> 3) << 4) | (x >> 3);
    int l = ((y & 7) << 3) | (x & 7);
    return (w << 6) | l;
}
__device__ __forceinline__ int orig_of(int s) {
    int w = s >> 6, l = s & 63;
    int py = w >> 4, px = w & 15, ly = l >> 3, lx = l & 7;
    return (((py << 3) + ly) << 7) + ((px << 3) + lx);
}

// ---------------- decode: pbox/pkey + trimmed word hulls (atomics) + outlier list ----------------
__global__ void decode_kernel(const float4* __restrict__ loc, const float* __restrict__ cls,
                              float4* __restrict__ boxes, float* __restrict__ score,
                              float4* __restrict__ pbox, u64* __restrict__ pkey,
                              u64* __restrict__ rec8,
                              u32* __restrict__ hx1n, u32* __restrict__ hy1n,
                              u32* __restrict__ hx2e, u32* __restrict__ hy2e,
                              u32* __restrict__ ocp, u16* __restrict__ olist) {
    int i = blockIdx.x * 256 + threadIdx.x;
    if (i >= N_ANCH) return;
    float4 l = loc[i];
    int y = i >> 7;        // FM_W = 128
    int x = i & 127;
    float cx = (x + 0.5f) * 8.0f;   // exact
    float cy = (y + 0.5f) * 8.0f;   // exact
    float px = __fadd_rn(__fmul_rn(l.x, 32.0f), cx);
    float py = __fadd_rn(__fmul_rn(l.y, 32.0f), cy);
    float pw = __fmul_rn(expf(l.z), 32.0f);
    float ph = __fmul_rn(expf(l.w), 32.0f);
    float hx = __fmul_rn(pw, 0.5f);
    float hy = __fmul_rn(ph, 0.5f);
    float x1 = __fsub_rn(px, hx), y1 = __fsub_rn(py, hy);
    float x2 = __fadd_rn(px, hx), y2 = __fadd_rn(py, hy);
    float4 b; b.x = x1; b.y = y1; b.z = x2; b.w = y2;
    boxes[i] = b;

    const float4* cr = (const float4*)(cls + (size_t)i * NCLS);
    float mx = -INFINITY;
#pragma unroll
    for (int k = 0; k < 16; ++k) {
        float4 v = cr[k];
        mx = fmaxf(mx, fmaxf(fmaxf(v.x, v.y), fmaxf(v.z, v.w)));
    }
    float s;
    if (mx >= 0.0f) {
        float e = expf(-mx);
        s = __fdiv_rn(1.0f, __fadd_rn(1.0f, e));
    } else {
        float e = expf(mx);
        s = __fdiv_rn(e, __fadd_rn(1.0f, e));
    }
    score[i] = s;
    float se = (s > 0.5f) ? s : -INFINITY;   // score_eff
    u32 u = __float_as_uint(se);
    u = (u & 0x80000000u) ? ~u : (u | 0x80000000u);   // ascending; valid >= 0x80000000

    int si = s_of(i);
    int W = si >> 6;
    bool valid = (u >= 0x80000000u);
    bool big = ((x2 - x1) > 128.0f) || ((y2 - y1) > 128.0f);
    pbox[si] = b;
    pkey[si] = ((u64)u << 32) | (u32)(~(u32)i);       // earlier(j,i) <=> k64_j > k64_i
    rec8[(size_t)si * 8] = 0ull;

    if (valid) {
        if (!big) {
            atomicMax(&hx1n[W], ~encf(x1));
            atomicMax(&hy1n[W], ~encf(y1));
            atomicMax(&hx2e[W], encf(x2));
            atomicMax(&hy2e[W], encf(y2));
        } else {
            u32 o = atomicAdd(ocp, 1u);
            if (o < OCAP) olist[o] = (u16)si;
        }
    }
}

// ---------------- pairs1: window tests -> compact global (row,W) list; + outlier pass ----------------
// 192 blocks x 1024 thr. Block rg owns rows = word rg's 64 boxes.
__global__ void __launch_bounds__(1024)
pairs1_kernel(const float4* __restrict__ pbox, const u64* __restrict__ pkey,
              u64* __restrict__ rec8, u8* __restrict__ ovw, u64* __restrict__ ovm,
              const u32* __restrict__ hx1n, const u32* __restrict__ hy1n,
              const u32* __restrict__ hx2e, const u32* __restrict__ hy2e,
              const u32* __restrict__ ocp, const u16* __restrict__ olist,
              u32* __restrict__ paircnt, u32* __restrict__ plist) {
    __shared__ float4 rbox[64];  __shared__ u64 rk[64];
    __shared__ float4 wb[TOTW];
    __shared__ u32 pbuf[12288];
    __shared__ u32 pcnt;
    __shared__ u32 pbase;
    __shared__ float4 obox[512]; __shared__ u64 okey[512]; __shared__ u16 osid[512];

    int tid = threadIdx.x;
    int wave = tid >> 6, lane = tid & 63;
    int rg = blockIdx.x;
    if (tid == 0) pcnt = 0;
    if (tid < 64) {
        rbox[tid] = pbox[(rg << 6) + tid];
        rk[tid] = pkey[(rg << 6) + tid];
    }
    if (tid < TOTW) {
        float4 h;
        h.x = decf(~hx1n[tid]); h.y = decf(~hy1n[tid]);
        h.z = decf(hx2e[tid]);  h.w = decf(hy2e[tid]);
        wb[tid] = h;                       // empty word -> NaNs -> never passes
    }
    __syncthreads();

    // phase 1: 64 rows x 192 words window tests -> pair list
    {
        int row = tid >> 4, wq = tid & 15;
        float4 bi = rbox[row];
        bool v = (rk[row] >> 63) != 0ull;
        u32 pm = 0;
#pragma unroll
        for (int k = 0; k < 12; ++k) {
            int W = wq * 12 + k;
            float4 h = wb[W];
            bool pass = v && (bi.x < h.z) && (h.x < bi.z) && (bi.y < h.w) && (h.y < bi.w);
            pm |= ((u32)pass) << k;
        }
        int nl = __popc(pm);
        u32 off = 0;
        if (nl) off = atomicAdd(&pcnt, (u32)nl);
        u32 rbase = ((u32)((rg << 6) + row)) << 8;
        while (pm) {
            int k = __ffs(pm) - 1; pm &= pm - 1;
            pbuf[off++] = rbase | (u32)(wq * 12 + k);
        }
    }
    __syncthreads();
    if (tid == 0) pbase = atomicAdd(paircnt, pcnt);
    __syncthreads();
    {
        u32 n = pcnt, b0 = pbase;
        for (u32 k = tid; k < n; k += 1024) plist[b0 + k] = pbuf[k];
    }

    // phase 3: all rows vs outlier (big) boxes, staged in chunks of 512
    u32 ocn = *ocp;
    if (ocn > OCAP) ocn = OCAP;
    for (u32 base = 0; base < ocn; base += 512) {
        u32 cnt = (ocn - base < 512u) ? (ocn - base) : 512u;
        __syncthreads();
        if (tid < cnt) {
            u16 sj = olist[base + tid];
            obox[tid] = pbox[sj]; okey[tid] = pkey[sj]; osid[tid] = sj;
        }
        __syncthreads();
        for (int rr = 0; rr < 4; ++rr) {
            int row = wave * 4 + rr;
            u64 ki = rk[row];
            if (!(ki >> 63)) continue;     // invalid row: wave-uniform skip
            float4 bi = rbox[row];
            float ai = area_of(bi);
            for (u32 j0 = 0; j0 < cnt; j0 += 64) {
                u32 jj = j0 + lane;
                bool pred = false;
                u16 sj = 0;
                if (jj < cnt) {
                    sj = osid[jj];
                    float4 bj = obox[jj];
                    pred = (okey[jj] > ki) && iou_gt(bi, ai, bj, area_of(bj));
                }
                if (pred) {
                    int r = (rg << 6) + row;
                    u32 slot = atomicAdd((u32*)&rec8[(size_t)r * 8], 1u);
                    u8 Wo = (u8)(sj >> 6);
                    u64 mm = 1ull << (sj & 63);
                    if (slot < 6) {
                        ((u8*)&rec8[(size_t)r * 8 + 1])[slot] = Wo;
                        rec8[(size_t)r * 8 + 2 + slot] = mm;
                    } else if (slot < 6u + CAPO) {
                        ovw[(size_t)r * CAPO + slot - 6] = Wo;
                        ovm[(size_t)r * CAPO + slot - 6] = mm;
                    }
                }
            }
        }
    }
}

// ---------------- pairs2: wave-per-(row,word) pair, grid-stride, fully parallel ----------------
__global__ void __launch_bounds__(256)
pairs2_kernel(const float4* __restrict__ pbox, const u64* __restrict__ pkey,
              const u32* __restrict__ paircnt, const u32* __restrict__ plist,
              u64* __restrict__ rec8, u8* __restrict__ ovw, u64* __restrict__ ovm) {
    u32 cnt = *paircnt;
    int lane = threadIdx.x & 63;
    u32 gw = (blockIdx.x * 256 + threadIdx.x) >> 6;
    u32 nw = gridDim.x * 4;
    for (u32 t = gw; t < cnt; t += nw) {
        u32 e = plist[t];
        u32 r = e >> 8;
        u32 W = e & 255u;
        float4 bi = pbox[r];               // wave-uniform broadcast load
        u64 ki = pkey[r];
        float ai = area_of(bi);
        int j = (int)(W << 6) + lane;
        float4 bj = pbox[j];               // coalesced 1KB
        u64 kj = pkey[j];                  // coalesced 512B
        bool pred = (kj > ki) && iou_gt(bi, ai, bj, area_of(bj));
        u64 mm = __ballot(pred);
        if (lane == 0 && mm) {
            u32 slot = atomicAdd((u32*)&rec8[(size_t)r * 8], 1u);
            if (slot < 6) {
                ((u8*)&rec8[(size_t)r * 8 + 1])[slot] = (u8)W;
                rec8[(size_t)r * 8 + 2 + slot] = mm;
            } else if (slot < 6u + CAPO) {
                ovw[(size_t)r * CAPO + slot - 6] = (u8)W;
                ovm[(size_t)r * CAPO + slot - 6] = mm;
            }
        }
    }
}

// ---------------- solve: synchronous fixpoint; s-space; fused output ----------------
__global__ void __launch_bounds__(1024)
solve_kernel(const u64* __restrict__ rec8, const u8* __restrict__ ovw,
             const u64* __restrict__ ovm, const float4* __restrict__ boxes,
             const float* __restrict__ score, float* __restrict__ out) {
    __shared__ u64 kept[TOTW];
    __shared__ u64 dec[TOTW];
    __shared__ int changed;
    int tid = threadIdx.x;
    for (int k = tid; k < TOTW; k += 1024) { kept[k] = 0ull; dec[k] = 0ull; }
    __syncthreads();

    u32 undec = 0;
#pragma unroll
    for (int b = 0; b < 12; ++b) {
        int i = tid + (b << 10);                  // s-space
        if (score[orig_of(i)] > 0.5f) undec |= (1u << b);
        else atomicOr(&dec[i >> 6], 1ull << (i & 63));
    }
    __syncthreads();

    for (int round = 0; round < 12300; ++round) {
        if (tid == 0) changed = 0;
        __syncthreads();
        u32 dkeep = 0, dkill = 0;
        u32 u = undec;
        while (u) {
            int b = __ffs(u) - 1; u &= u - 1;
            int i = tid + (b << 10);
            const ulonglong4* rp = (const ulonglong4*)&rec8[(size_t)i * 8];
            ulonglong4 RA = rp[0];
            u32 wc = (u32)RA.x;
            u64 wb = RA.y;
            u32 w0 = (u32)(wb & 0xFF), w1 = (u32)((wb >> 8) & 0xFF);
            u64 anyk = 0, anyu = 0;
            if (wc > 0) { u64 m = RA.z; anyu |= m & ~dec[w0]; anyk |= m & kept[w0]; }
            if (wc > 1) { u64 m = RA.w; anyu |= m & ~dec[w1]; anyk |= m & kept[w1]; }
            if (wc > 2) {
                ulonglong4 RB = rp[1];
                u32 w2 = (u32)((wb >> 16) & 0xFF), w3 = (u32)((wb >> 24) & 0xFF);
                u32 w4 = (u32)((wb >> 32) & 0xFF), w5 = (u32)((wb >> 40) & 0xFF);
                { u64 m = RB.x; anyu |= m & ~dec[w2]; anyk |= m & kept[w2]; }
                if (wc > 3) { u64 m = RB.y; anyu |= m & ~dec[w3]; anyk |= m & kept[w3]; }
                if (wc > 4) { u64 m = RB.z; anyu |= m & ~dec[w4]; anyk |= m & kept[w4]; }
                if (wc > 5) { u64 m = RB.w; anyu |= m & ~dec[w5]; anyk |= m & kept[w5]; }
            }
            if (wc > 6) {
                u32 we = (wc <= (u32)(6 + CAPO)) ? wc : (u32)(6 + CAPO);
                for (u32 k = 6; k < we; ++k) {
                    u32 Wo = ovw[(size_t)i * CAPO + (k - 6)];
                    u64 m = ovm[(size_t)i * CAPO + (k - 6)];
                    anyu |= m & ~dec[Wo]; anyk |= m & kept[Wo];
                }
            }
            if (anyk) dkill |= (1u << b);
            else if (!anyu) dkeep |= (1u << b);
        }
        __syncthreads();
        u32 dmask = dkeep | dkill;
        if (dmask) {
            changed = 1;
            u32 m2 = dmask;
            while (m2) {
                int b = __ffs(m2) - 1; m2 &= m2 - 1;
                int i = tid + (b << 10);
                if (dkeep & (1u << b)) atomicOr(&kept[i >> 6], 1ull << (i & 63));
                atomicOr(&dec[i >> 6], 1ull << (i & 63));
            }
            undec &= ~dmask;
        }
        __syncthreads();
        int ch = changed;
        __syncthreads();
        if (ch == 0) break;
    }

    // output: map s -> orig
#pragma unroll
    for (int b = 0; b < 12; ++b) {
        int i = tid + (b << 10);
        int og = orig_of(i);
        float m = ((kept[i >> 6] >> (i & 63)) & 1ull) ? 1.0f : 0.0f;
        float4 bx = boxes[og];
        float s = score[og];
        out[(size_t)og * 5 + 0] = __fmul_rn(bx.x, m);
        out[(size_t)og * 5 + 1] = __fmul_rn(bx.y, m);
        out[(size_t)og * 5 + 2] = __fmul_rn(bx.z, m);
        out[(size_t)og * 5 + 3] = __fmul_rn(bx.w, m);
        out[(size_t)og * 5 + 4] = __fmul_rn(s, m);
    }
}

extern "C" void kernel_launch(void* const* d_in, const int* in_sizes, int n_in,
                              void* d_out, int out_size, void* d_ws, size_t ws_size,
                              hipStream_t stream) {
    const float4* loc = (const float4*)d_in[0];
    const float* cls = (const float*)d_in[1];
    char* ws = (char*)d_ws;

    float4* boxes   = (float4*)(ws + 0);           // 196608
    float*  score   = (float*) (ws + 196608);      // 49152
    float4* pbox    = (float4*)(ws + 245760);      // 196608
    u64*    pkey    = (u64*)   (ws + 442368);      // 98304
    u64*    rec8    = (u64*)   (ws + 540672);      // 786432
    u32*    hx1n    = (u32*)   (ws + 1327104);     // 768
    u32*    hy1n    = (u32*)   (ws + 1327872);     // 768
    u32*    hx2e    = (u32*)   (ws + 1328640);     // 768
    u32*    hy2e    = (u32*)   (ws + 1329408);     // 768
    u32*    ocp     = (u32*)   (ws + 1330176);     // 4
    u32*    paircnt = (u32*)   (ws + 1330180);     // 4
    u16*    olist   = (u16*)   (ws + 1330240);     // 8192
    u32*    plist   = (u32*)   (ws + 1338432);     // 9437184 (worst-case 2.36M pairs)
    u8*     ovw     = (u8*)    (ws + 10775616);    // 12582912
    u64*    ovm     = (u64*)   (ws + 23358528);    // 100663296 (end ~118MB; ws ~256MB)
    float*  out     = (float*)d_out;

    hipMemsetAsync(ws + 1327104, 0, 3136, stream);   // hulls + ocp + paircnt
    decode_kernel<<<48, 256, 0, stream>>>(loc, cls, boxes, score, pbox, pkey, rec8,
                                          hx1n, hy1n, hx2e, hy2e, ocp, olist);
    pairs1_kernel<<<TOTW, 1024, 0, stream>>>(pbox, pkey, rec8, ovw, ovm,
                                             hx1n, hy1n, hx2e, hy2e, ocp, olist,
                                             paircnt, plist);
    pairs2_kernel<<<2048, 256, 0, stream>>>(pbox, pkey, paircnt, plist, rec8, ovw, ovm);
    solve_kernel<<<1, 1024, 0, stream>>>(rec8, ovw, ovm, boxes, score, out);
}